// Round 1
// 101.303 us; speedup vs baseline: 1.0804x; 1.0804x over previous
//
#include <hip/hip_runtime.h>
#include <math.h>

// Problem constants
#define B 32
#define T 32
#define L 196
#define S 512
#define D 512

// -------------------------------------------------------------------------
// K1: w1v[s] = sum_d W1[s,d] * V[d]. One wave per row, float4 dot + shuffle
// reduce. grid = 128 blocks x 4 waves = 512 rows.
// -------------------------------------------------------------------------
__global__ void k_w1v(const float* __restrict__ W1, const float* __restrict__ V,
                      float* __restrict__ w1v) {
    const int wave = threadIdx.x >> 6, lane = threadIdx.x & 63;
    const int row  = blockIdx.x * 4 + wave;
    const float4* r  = (const float4*)(W1 + (size_t)row * D);
    const float4* v4 = (const float4*)V;
    float4 a = r[lane], bb = v4[lane];
    float4 c = r[64 + lane], dd = v4[64 + lane];
    float p = (a.x * bb.x + a.y * bb.y + a.z * bb.z + a.w * bb.w) +
              (c.x * dd.x + c.y * dd.y + c.z * dd.z + c.w * dd.w);
    for (int off = 32; off; off >>= 1) p += __shfl_down(p, off);
    if (lane == 0) w1v[row] = p;
}

// -------------------------------------------------------------------------
// K2: sc[b*L+l] = x_static[b,l,:] . w1v  — one wave per (b,l) row.
// rows = B*L = 6272, 4 waves/block -> 1568 blocks. HBM-BW bound (~13 MB).
// -------------------------------------------------------------------------
__global__ void k_scores(const float* __restrict__ xs, const float* __restrict__ w1v,
                         float* __restrict__ sc) {
    const int wave = threadIdx.x >> 6, lane = threadIdx.x & 63;
    const int row  = blockIdx.x * 4 + wave;
    if (row >= B * L) return;
    const float4* r  = (const float4*)(xs + (size_t)row * S);
    const float4* v4 = (const float4*)w1v;
    float4 a = r[lane], bb = v4[lane];
    float4 c = r[64 + lane], dd = v4[64 + lane];
    float p = (a.x * bb.x + a.y * bb.y + a.z * bb.z + a.w * bb.w) +
              (c.x * dd.x + c.y * dd.y + c.z * dd.z + c.w * dd.w);
    for (int off = 32; off; off >>= 1) p += __shfl_down(p, off);
    if (lane == 0) sc[row] = p;
}

// -------------------------------------------------------------------------
// K3': fused ctx + partial c-projection. One block per (b, 64-col s-chunk),
// 512 threads (8 waves -> 2x the in-flight loads of the old 4-wave version).
// Phase A: redundant softmax over sc[b,:] (cheap).
// Phase B: cs[s] = sum_l attn[l]*xs[b,l,s] for the 64-col chunk.
// Phase C: cpp[b][chunk][d] = sum_{s in chunk} cs[s]*W3[D+s, d] for ALL 512 d
//          (one d per thread). Deterministic partials, summed in k_out.
// grid = (S/64=8, B) = 256 blocks. Kills the old k_cproj launch entirely.
// -------------------------------------------------------------------------
__global__ __launch_bounds__(512) void k_ctx_cp(const float* __restrict__ xs,
                                                const float* __restrict__ sc,
                                                const float* __restrict__ W3,
                                                float* __restrict__ cpp) {
    __shared__ float attn[512];
    __shared__ float red[16];
    __shared__ float part[8][64];
    __shared__ float cs[64];
    const int b = blockIdx.y, s0 = blockIdx.x * 64, tid = threadIdx.x;
    const int lane = tid & 63, wave = tid >> 6;

    // Phase A: softmax over l (196 values, threads 196..511 idle-safe)
    float v = (tid < L) ? sc[b * L + tid] : -1e30f;
    float m = v;
    for (int off = 32; off; off >>= 1) m = fmaxf(m, __shfl_down(m, off));
    if (lane == 0) red[wave] = m;
    __syncthreads();
    m = fmaxf(fmaxf(fmaxf(red[0], red[1]), fmaxf(red[2], red[3])),
              fmaxf(fmaxf(red[4], red[5]), fmaxf(red[6], red[7])));
    float e = (tid < L) ? expf(v - m) : 0.f;
    attn[tid] = e;
    float ssum = e;
    for (int off = 32; off; off >>= 1) ssum += __shfl_down(ssum, off);
    if (lane == 0) red[8 + wave] = ssum;
    __syncthreads();
    const float inv = 1.f / (red[8] + red[9] + red[10] + red[11] +
                             red[12] + red[13] + red[14] + red[15]);

    // Phase B: ctx for this 64-col s-chunk. Waves interleave l (stride 8).
    const float* xb = xs + (size_t)b * L * S + s0 + lane;
    float a[8];
#pragma unroll
    for (int u = 0; u < 8; ++u) a[u] = 0.f;
    int l = wave;
    for (int g = 0; g < 3; ++g) {       // 3 groups x 8 = 24 iters per wave
#pragma unroll
        for (int u = 0; u < 8; ++u)
            a[u] = fmaf(attn[l + u * 8], xb[(size_t)(l + u * 8) * S], a[u]);
        l += 64;
    }
    if (wave < 4)                       // remainder: l = 192+wave < 196
        a[0] = fmaf(attn[l], xb[(size_t)l * S], a[0]);
    float acc = ((a[0] + a[1]) + (a[2] + a[3])) + ((a[4] + a[5]) + (a[6] + a[7]));
    part[wave][lane] = acc;
    __syncthreads();
    if (wave == 0) {
        float t = ((part[0][lane] + part[1][lane]) + (part[2][lane] + part[3][lane])) +
                  ((part[4][lane] + part[5][lane]) + (part[6][lane] + part[7][lane]));
        cs[lane] = t * inv;             // fold 1/sum into ctx once
    }
    __syncthreads();

    // Phase C: 512 threads = 512 d-columns, 64-s dot against W3 lower rows.
    const float* wr = W3 + ((size_t)(D + s0)) * D + tid;
    float a2[4] = {0.f, 0.f, 0.f, 0.f};
#pragma unroll
    for (int s = 0; s < 64; s += 4) {
#pragma unroll
        for (int u = 0; u < 4; ++u)
            a2[u] = fmaf(cs[s + u], wr[(size_t)(s + u) * D], a2[u]);
    }
    cpp[((size_t)b * 8 + blockIdx.x) * D + tid] = (a2[0] + a2[1]) + (a2[2] + a2[3]);
}

// -------------------------------------------------------------------------
// K5': out[b,t,d] = x[b,t,:] . W3[:D,d] + b3[d] + sum_chunk cpp[b][chunk][d].
// t-tile 8, d-chunk 256, k split across 4 waves (128 k each). W3 loaded as
// float4 (1 KB per wave-instr, 4x the old dword width); halves W3 L2 traffic
// vs the old t-tile-4 version (128 MB total). 8-deep load pipeline; VALU
// floor for the 537 MFLOP GEMM is 3.4 us. grid = (2, T/8=4, B) = 256 blocks.
// -------------------------------------------------------------------------
__global__ __launch_bounds__(256) void k_out(const float* __restrict__ x,
                                             const float* __restrict__ W3,
                                             const float* __restrict__ cpp,
                                             const float* __restrict__ b3,
                                             float* __restrict__ out) {
    __shared__ float xlt[D * 8];        // [k][t] transposed, 16 KB
    __shared__ float red[4 * 8 * 256];  // [wave][t][d'], 32 KB
    const int b = blockIdx.z, t0 = blockIdx.y * 8, d0 = blockIdx.x * 256;
    const int tid = threadIdx.x, lane = tid & 63, wave = tid >> 6;

    // Stage x[b, t0..t0+7, :] transposed (global reads coalesced in k).
    const float* xb = x + ((size_t)b * T + t0) * D;
    for (int idx = tid; idx < 8 * D; idx += 256) {
        const int t = idx >> 9;         // t within tile
        const int k = idx & (D - 1);
        xlt[k * 8 + t] = xb[(size_t)t * D + k];
    }
    __syncthreads();

    // Each wave: 128 k-rows x 256 d-cols. Thread owns d-quad d0+lane*4.
    const int kbeg = wave * 128;
    const float* wp = W3 + (size_t)kbeg * D + d0 + (lane << 2);
    float4 acc[8];
#pragma unroll
    for (int t = 0; t < 8; ++t) acc[t] = make_float4(0.f, 0.f, 0.f, 0.f);

#pragma unroll 8
    for (int kk = 0; kk < 128; ++kk) {
        const float4 w4 = *(const float4*)(wp + (size_t)kk * D);   // coalesced 1KB/wave
        const float4 xa = *(const float4*)&xlt[(kbeg + kk) * 8];   // broadcast b128
        const float4 xc = *(const float4*)&xlt[(kbeg + kk) * 8 + 4];
        const float xt[8] = {xa.x, xa.y, xa.z, xa.w, xc.x, xc.y, xc.z, xc.w};
#pragma unroll
        for (int t = 0; t < 8; ++t) {
            acc[t].x = fmaf(xt[t], w4.x, acc[t].x);
            acc[t].y = fmaf(xt[t], w4.y, acc[t].y);
            acc[t].z = fmaf(xt[t], w4.z, acc[t].z);
            acc[t].w = fmaf(xt[t], w4.w, acc[t].w);
        }
    }

    // Cross-wave reduction: red[wave][t][d'] (float4 stores, conflict-free).
    float* rw = red + ((wave * 8) << 8) + (lane << 2);
#pragma unroll
    for (int t = 0; t < 8; ++t) *(float4*)(rw + (t << 8)) = acc[t];
    __syncthreads();

    // Epilogue: thread owns d' = tid for all 8 t. Add b3 + 8 cpp slabs.
    float cpsum = b3[d0 + tid];
#pragma unroll
    for (int j = 0; j < 8; ++j) cpsum += cpp[((size_t)b * 8 + j) * D + d0 + tid];
    float* ob = out + ((size_t)b * T + t0) * D + d0 + tid;
#pragma unroll
    for (int t = 0; t < 8; ++t) {
        const float v = (red[(0 * 8 + t) * 256 + tid] + red[(1 * 8 + t) * 256 + tid]) +
                        (red[(2 * 8 + t) * 256 + tid] + red[(3 * 8 + t) * 256 + tid]);
        ob[(size_t)t * D] = v + cpsum;
    }
}

extern "C" void kernel_launch(void* const* d_in, const int* in_sizes, int n_in,
                              void* d_out, int out_size, void* d_ws, size_t ws_size,
                              hipStream_t stream) {
    const float* x  = (const float*)d_in[0];   // [B,T,D]
    const float* xs = (const float*)d_in[1];   // [B,L,S]
    const float* W1 = (const float*)d_in[3];   // [S,D]
    const float* W3 = (const float*)d_in[5];   // [D+S, D]
    const float* b3 = (const float*)d_in[7];   // [D]
    const float* V  = (const float*)d_in[8];   // [D,1]
    float* out = (float*)d_out;

    // Workspace layout (floats).
    float* ws  = (float*)d_ws;
    float* w1v = ws;                   // [0, 512)
    float* sc  = ws + 512;             // [512, 6784)   B*L = 6272
    float* cpp = ws + 8192;            // [8192, 139264) B*8*D partial c-proj

    k_w1v   <<<dim3(S / 4),         dim3(256), 0, stream>>>(W1, V, w1v);
    k_scores<<<dim3(B * L / 4),     dim3(256), 0, stream>>>(xs, w1v, sc);
    k_ctx_cp<<<dim3(S / 64, B),     dim3(512), 0, stream>>>(xs, sc, W3, cpp);
    k_out   <<<dim3(2, T / 8, B),   dim3(256), 0, stream>>>(x, W3, cpp, b3, out);
}